// Round 2
// baseline (111.547 us; speedup 1.0000x reference)
//
#include <hip/hip_runtime.h>

#define T_LEN 8192
#define FLOOR_C 1e-6f

__device__ __forceinline__ float fast_log2(float v) { return __builtin_amdgcn_logf(v); }
__device__ __forceinline__ float fast_exp2(float v) { return __builtin_amdgcn_exp2f(v); }

__device__ __forceinline__ float pcen_one(float xv, float smo, float alpha,
                                          float delta, float root, float droot,
                                          bool root_is_half) {
    // smooth_term = (FLOOR + smo)^(-alpha)
    float st = fast_exp2(-alpha * fast_log2(FLOOR_C + smo));
    float inner = xv * st + delta;
    float pr = root_is_half ? sqrtf(inner) : fast_exp2(root * fast_log2(inner));
    return pr - droot;
}

__global__ __launch_bounds__(256) void pcen_kernel(
    const float* __restrict__ x,
    const float* __restrict__ alpha_p,
    const float* __restrict__ delta_p,
    const float* __restrict__ root_p,
    const float* __restrict__ sc_p,
    float* __restrict__ out,
    int nrows)
{
    const float alpha = alpha_p[0];
    const float delta = delta_p[0];
    const float root  = root_p[0];
    float s = sc_p[0];
    s = fminf(fmaxf(s, 0.001f), 0.999f);
    const float oms = 1.0f - s;

    const int wave = threadIdx.x >> 6;
    const int lane = threadIdx.x & 63;
    const int row  = blockIdx.x * 4 + wave;
    if (row >= nrows) return;

    const float s2 = s * s;
    const float s3 = s2 * s;
    const float s4 = s2 * s2;
    // scan multipliers: (s^4)^(2^k)
    const float m0 = s4;        // s^4
    const float m1 = m0 * m0;   // s^8
    const float m2 = m1 * m1;   // s^16
    const float m3 = m2 * m2;   // s^32
    const float m4 = m3 * m3;   // s^64
    const float m5 = m4 * m4;   // s^128
    const float s256 = m5 * m5; // s^256
    // s^(4*lane), once per thread (s>0 so log2 is safe)
    const float sp4i  = fast_exp2(4.0f * (float)lane * fast_log2(s));
    const bool  root_is_half = (root == 0.5f);
    const float droot = root_is_half ? sqrtf(delta)
                                     : fast_exp2(root * fast_log2(delta));

    const float4* __restrict__ xrow = (const float4*)(x + (size_t)row * T_LEN);
    float4* __restrict__ orow = (float4*)(out + (size_t)row * T_LEN);

    const int nchunks = T_LEN / 256;  // 256 elements per wave-chunk
    float carry = 0.0f;               // smoothed value just before current chunk

    float4 xc = xrow[lane];  // prefetch chunk 0
    for (int c = 0; c < nchunks; ++c) {
        float4 xn;
        if (c + 1 < nchunks) xn = xrow[(c + 1) * 64 + lane];

        // Local affine map over this lane's 4 elements: f(p) = s^4*p + B
        float B = oms * (xc.x * s3 + xc.y * s2 + xc.z * s + xc.w);

        // Inclusive wave scan (Hillis-Steele) of B with per-lane-step factor s^4
        float P = B;
        float t;
        t = __shfl_up(P, 1);  if (lane >= 1)  P += m0 * t;
        t = __shfl_up(P, 2);  if (lane >= 2)  P += m1 * t;
        t = __shfl_up(P, 4);  if (lane >= 4)  P += m2 * t;
        t = __shfl_up(P, 8);  if (lane >= 8)  P += m3 * t;
        t = __shfl_up(P, 16); if (lane >= 16) P += m4 * t;
        t = __shfl_up(P, 32); if (lane >= 32) P += m5 * t;

        // Exclusive prefix (composed B of lanes < i)
        float X = __shfl_up(P, 1);
        if (lane == 0) X = 0.0f;

        // State entering this lane's first element
        float state = sp4i * carry + X;

        // Sequential EMA over this lane's 4 elements (exact)
        float smo0 = s * state + oms * xc.x;
        float smo1 = s * smo0  + oms * xc.y;
        float smo2 = s * smo1  + oms * xc.z;
        float smo3 = s * smo2  + oms * xc.w;

        // Carry to next chunk: apply whole-chunk map to carry
        float Plast = __shfl(P, 63);
        carry = s256 * carry + Plast;

        float4 o;
        o.x = pcen_one(xc.x, smo0, alpha, delta, root, droot, root_is_half);
        o.y = pcen_one(xc.y, smo1, alpha, delta, root, droot, root_is_half);
        o.z = pcen_one(xc.z, smo2, alpha, delta, root, droot, root_is_half);
        o.w = pcen_one(xc.w, smo3, alpha, delta, root, droot, root_is_half);
        orow[c * 64 + lane] = o;

        xc = xn;
    }
}

extern "C" void kernel_launch(void* const* d_in, const int* in_sizes, int n_in,
                              void* d_out, int out_size, void* d_ws, size_t ws_size,
                              hipStream_t stream) {
    const float* x       = (const float*)d_in[0];
    const float* alpha_p = (const float*)d_in[1];
    const float* delta_p = (const float*)d_in[2];
    const float* root_p  = (const float*)d_in[3];
    const float* sc_p    = (const float*)d_in[4];
    float* out = (float*)d_out;

    int nrows = in_sizes[0] / T_LEN;       // 64*128 = 8192 rows
    int blocks = (nrows + 3) / 4;          // 4 waves (rows) per 256-thread block

    pcen_kernel<<<blocks, 256, 0, stream>>>(x, alpha_p, delta_p, root_p, sc_p,
                                            out, nrows);
}